// Round 8
// baseline (486.321 us; speedup 1.0000x reference)
//
#include <hip/hip_runtime.h>

// B=128 trajectories, N=20000 vars, M=85400 clauses, K=3 literals/clause.
// Inputs: v(B*N) f32, xl(B*M) f32, xs(B*M) f32, param(6) f32,
//         input_sign(B*M*K) f32, input_idx(B*M*K) i32
// Outputs concat: C(B*M), grad_v(B*N), dxl(B*M), dxs(B*M)  -- all f32

#define NMAX 20000     // sv (80KB) + sg (80KB) = 160KB LDS -> 1 block/CU
#define BPB  2         // clause-chunks per batch element -> grid 256 = 1/CU

typedef int   int4v   __attribute__((ext_vector_type(4)));
typedef float float4v __attribute__((ext_vector_type(4)));

__device__ __forceinline__ void clause_math(
    float a0, float a1, float a2, float xlv, float xsv, float zeta,
    float& C, float& g0, float& g1, float& g2)
{
    // top-2 with jax.lax.top_k tie semantics (first occurrence wins argmax)
    int k0; float m0, m1;
    if (a0 >= a1) {
        if (a0 >= a2) { k0 = 0; m0 = a0; m1 = fmaxf(a1, a2); }
        else          { k0 = 2; m0 = a2; m1 = fmaxf(a0, a1); }
    } else {
        if (a1 >= a2) { k0 = 1; m0 = a1; m1 = fmaxf(a0, a2); }
        else          { k0 = 2; m0 = a2; m1 = fmaxf(a0, a1); }
    }
    C = (1.f - m0) * 0.5f;
    const float T2 = (1.f - m1) * 0.5f;
    const float gl = xlv * xsv;
    const float rC = C * ((1.f + zeta * xlv) * (1.f - xsv));
    g0 = (k0 == 0 ? T2 : C) * gl + (k0 == 0 ? rC : 0.f);
    g1 = (k0 == 1 ? T2 : C) * gl + (k0 == 1 ? rC : 0.f);
    g2 = (k0 == 2 ? T2 : C) * gl + (k0 == 2 ? rC : 0.f);
}

// ---------- fast path: v + grad in LDS, 8-clause burst per iteration ----------
__global__ __launch_bounds__(1024, 4) void or_priv10(
    const float* __restrict__ v,
    const float* __restrict__ xl,
    const float* __restrict__ xs,
    const float* __restrict__ param,
    const float* __restrict__ sign,
    const int*   __restrict__ idx,
    float* __restrict__ outC,
    float* __restrict__ outdxl,
    float* __restrict__ outdxs,
    float* __restrict__ partial,   // [BPB][B][N]
    int N, int M, int B, int chunk)
{
    __shared__ float sv[NMAX];   // v slice (gathers stay in LDS -- R1 lesson)
    __shared__ float sg[NMAX];   // grad accumulator (stays in LDS -- R3 lesson)

    // XCD swizzle: the BPB=2 blocks of each b land on one XCD (v-stage L2 reuse)
    const int id  = blockIdx.x;
    const int cpx = gridDim.x >> 3;
    const int cid = ((gridDim.x & 7) == 0) ? ((id & 7) * cpx + (id >> 3)) : id;
    const int b   = cid >> 1;              // BPB == 2
    const int j   = cid & 1;
    const int tid = threadIdx.x;

    // stage v slice (coalesced float4) + zero grad
    {
        const float4v* __restrict__ v4 = (const float4v*)(v + (size_t)b * N);
        float4v* sv4 = (float4v*)sv;
        float4v* sg4 = (float4v*)sg;
        const int n4 = N >> 2;
        const float4v z = {0.f, 0.f, 0.f, 0.f};
        for (int i = tid; i < n4; i += 1024) {
            sv4[i] = v4[i];
            sg4[i] = z;
        }
        for (int i = (n4 << 2) + tid; i < N; i += 1024) {
            sv[i] = v[(size_t)b * N + i];
            sg[i] = 0.f;
        }
    }
    __syncthreads();

    const float alpha = param[0], beta = param[1], gamma = param[2];
    const float delta = param[3], eps  = param[4], zeta  = param[5];

    const int mstart = j * chunk;                 // chunk is a multiple of 8
    const int mend   = min(M, mstart + chunk);
    const int mlen   = mend - mstart;

    // process 4 clauses from vectors (Ia,Ib,Ic / Sa,Sb,Sc / XL,XS), base BB
    #define PROC4(Ia, Ib, Ic, Sa, Sb, Sc, XL, XS, BB) do {                  \
        const int   _ii[12] = {Ia.x, Ia.y, Ia.z, Ia.w, Ib.x, Ib.y, Ib.z,    \
                               Ib.w, Ic.x, Ic.y, Ic.z, Ic.w};               \
        const float _ss[12] = {Sa.x, Sa.y, Sa.z, Sa.w, Sb.x, Sb.y, Sb.z,    \
                               Sb.w, Sc.x, Sc.y, Sc.z, Sc.w};               \
        const float _xlA[4] = {XL.x, XL.y, XL.z, XL.w};                     \
        const float _xsA[4] = {XS.x, XS.y, XS.z, XS.w};                     \
        float _Cv[4], _dxlv[4], _dxsv[4];                                   \
        _Pragma("unroll")                                                   \
        for (int c = 0; c < 4; ++c) {                                       \
            const int   _i0 = _ii[3*c], _i1 = _ii[3*c+1], _i2 = _ii[3*c+2]; \
            const float _s0 = _ss[3*c], _s1 = _ss[3*c+1], _s2 = _ss[3*c+2]; \
            const float _a0 = sv[_i0] * _s0;                                \
            const float _a1 = sv[_i1] * _s1;                                \
            const float _a2 = sv[_i2] * _s2;                                \
            float _C, _g0, _g1, _g2;                                        \
            clause_math(_a0, _a1, _a2, _xlA[c], _xsA[c], zeta,              \
                        _C, _g0, _g1, _g2);                                 \
            unsafeAtomicAdd(&sg[_i0], -_g0 * _s0);                          \
            unsafeAtomicAdd(&sg[_i1], -_g1 * _s1);                          \
            unsafeAtomicAdd(&sg[_i2], -_g2 * _s2);                          \
            _Cv[c]   = _C;                                                  \
            _dxlv[c] = -alpha * (_C - delta);                               \
            _dxsv[c] = -beta * (_xsA[c] + eps) * (_C - gamma);              \
        }                                                                   \
        const float4v _cv  = {_Cv[0], _Cv[1], _Cv[2], _Cv[3]};              \
        const float4v _lv  = {_dxlv[0], _dxlv[1], _dxlv[2], _dxlv[3]};      \
        const float4v _svo = {_dxsv[0], _dxsv[1], _dxsv[2], _dxsv[3]};      \
        __builtin_nontemporal_store(_cv,  (float4v*)(outC + (BB)));         \
        __builtin_nontemporal_store(_lv,  (float4v*)(outdxl + (BB)));       \
        __builtin_nontemporal_store(_svo, (float4v*)(outdxs + (BB)));       \
    } while (0)

    if (mlen > 0 && (mlen & 7) == 0) {
        const int ngroups = mlen >> 3;                  // 8 clauses per group
        const size_t eb = (size_t)b * M + mstart;

        for (int g = tid; g < ngroups; g += 1024) {
            const size_t base = eb + ((size_t)g << 3);  // 8 clauses, 32B-aligned
            const int4v*   __restrict__ ip = (const int4v*)(idx + base * 3);
            const float4v* __restrict__ sp = (const float4v*)(sign + base * 3);

            // 16-load burst: 6 idx + 6 sign + 2 xl + 2 xs, all dwordx4
            int4v   i0 = __builtin_nontemporal_load(ip + 0);
            int4v   i1 = __builtin_nontemporal_load(ip + 1);
            int4v   i2 = __builtin_nontemporal_load(ip + 2);
            int4v   i3 = __builtin_nontemporal_load(ip + 3);
            int4v   i4 = __builtin_nontemporal_load(ip + 4);
            int4v   i5 = __builtin_nontemporal_load(ip + 5);
            float4v s0 = __builtin_nontemporal_load(sp + 0);
            float4v s1 = __builtin_nontemporal_load(sp + 1);
            float4v s2 = __builtin_nontemporal_load(sp + 2);
            float4v s3 = __builtin_nontemporal_load(sp + 3);
            float4v s4 = __builtin_nontemporal_load(sp + 4);
            float4v s5 = __builtin_nontemporal_load(sp + 5);
            float4v xa = __builtin_nontemporal_load((const float4v*)(xl + base));
            float4v xb = __builtin_nontemporal_load((const float4v*)(xl + base + 4));
            float4v ya = __builtin_nontemporal_load((const float4v*)(xs + base));
            float4v yb = __builtin_nontemporal_load((const float4v*)(xs + base + 4));

            // keep-alive: all 16 loads feed this opaque asm -> none can be
            // sunk below it; compiler emits ONE wait here covering the burst.
            asm volatile(""
                : "+v"(i0), "+v"(i1), "+v"(i2), "+v"(i3), "+v"(i4), "+v"(i5),
                  "+v"(s0), "+v"(s1), "+v"(s2), "+v"(s3), "+v"(s4), "+v"(s5),
                  "+v"(xa), "+v"(xb), "+v"(ya), "+v"(yb));

            PROC4(i0, i1, i2, s0, s1, s2, xa, ya, base);
            PROC4(i3, i4, i5, s3, s4, s5, xb, yb, base + 4);
        }
    } else {
        // ragged tail fallback (not hit for M%8-compatible chunking)
        for (int m = mstart + tid; m < mend; m += 1024) {
            const size_t bm  = (size_t)b * M + m;
            const size_t bm3 = bm * 3;
            const int   i0 = idx[bm3 + 0], i1 = idx[bm3 + 1], i2 = idx[bm3 + 2];
            const float s0 = sign[bm3 + 0], s1 = sign[bm3 + 1], s2 = sign[bm3 + 2];
            const float a0 = sv[i0] * s0, a1 = sv[i1] * s1, a2 = sv[i2] * s2;
            const float xlv = xl[bm], xsv = xs[bm];
            float C, g0, g1, g2;
            clause_math(a0, a1, a2, xlv, xsv, zeta, C, g0, g1, g2);
            unsafeAtomicAdd(&sg[i0], -g0 * s0);
            unsafeAtomicAdd(&sg[i1], -g1 * s1);
            unsafeAtomicAdd(&sg[i2], -g2 * s2);
            outC[bm]   = C;
            outdxl[bm] = -alpha * (C - delta);
            outdxs[bm] = -beta * (xsv + eps) * (C - gamma);
        }
    }
    #undef PROC4

    __syncthreads();

    // flush grad accumulator to the per-(j,b) partial slab (cached stores:
    // reduce2 then hits L2/L3 instead of HBM)
    {
        float* __restrict__ pj = partial + ((size_t)j * B + b) * N;
        const float4v* sg4 = (const float4v*)sg;
        const int n4 = N >> 2;
        for (int i = tid; i < n4; i += 1024)
            ((float4v*)pj)[i] = sg4[i];
        for (int i = (n4 << 2) + tid; i < N; i += 1024) pj[i] = sg[i];
    }
}

__global__ __launch_bounds__(256) void reduce2(
    const float4v* __restrict__ p, float4v* __restrict__ out, int n4, int stride4)
{
    int i = blockIdx.x * 256 + threadIdx.x;
    const int gs = gridDim.x * 256;
    for (; i < n4; i += gs) {
        const float4v a = p[i];
        const float4v b = p[i + stride4];
        out[i] = a + b;
    }
}

// ---------- fallback path (round-1, global atomics) ----------
__global__ __launch_bounds__(256) void zero_f4(float4v* __restrict__ p, int n4) {
    int i = blockIdx.x * blockDim.x + threadIdx.x;
    int stride = gridDim.x * blockDim.x;
    const float4v z = {0.f, 0.f, 0.f, 0.f};
    for (; i < n4; i += stride) p[i] = z;
}

__global__ __launch_bounds__(256) void or_kernel(
    const float* __restrict__ v, const float* __restrict__ xl,
    const float* __restrict__ xs, const float* __restrict__ param,
    const float* __restrict__ sign, const int* __restrict__ idx,
    float* __restrict__ outC, float* __restrict__ gradv,
    float* __restrict__ outdxl, float* __restrict__ outdxs, int N, int M)
{
    const int m = blockIdx.x * blockDim.x + threadIdx.x;
    const int b = blockIdx.y;
    if (m >= M) return;
    const size_t bm = (size_t)b * M + m;
    const size_t bm3 = bm * 3;
    const int   i0 = idx[bm3 + 0], i1 = idx[bm3 + 1], i2 = idx[bm3 + 2];
    const float s0 = sign[bm3 + 0], s1 = sign[bm3 + 1], s2 = sign[bm3 + 2];
    const float* __restrict__ vb = v + (size_t)b * N;
    const float a0 = vb[i0] * s0, a1 = vb[i1] * s1, a2 = vb[i2] * s2;
    const float xlv = xl[bm], xsv = xs[bm];
    const float alpha = param[0], beta = param[1], gamma = param[2];
    const float delta = param[3], eps  = param[4], zeta  = param[5];

    float C, g0, g1, g2;
    clause_math(a0, a1, a2, xlv, xsv, zeta, C, g0, g1, g2);

    float* __restrict__ gb = gradv + (size_t)b * N;
    atomicAdd(&gb[i0], -g0 * s0);
    atomicAdd(&gb[i1], -g1 * s1);
    atomicAdd(&gb[i2], -g2 * s2);

    outC[bm]   = C;
    outdxl[bm] = -alpha * (C - delta);
    outdxs[bm] = -beta * (xsv + eps) * (C - gamma);
}

extern "C" void kernel_launch(void* const* d_in, const int* in_sizes, int n_in,
                              void* d_out, int out_size, void* d_ws, size_t ws_size,
                              hipStream_t stream) {
    const float* v     = (const float*)d_in[0];
    const float* xl    = (const float*)d_in[1];
    const float* xs    = (const float*)d_in[2];
    const float* param = (const float*)d_in[3];
    const float* sign  = (const float*)d_in[4];
    const int*   idx   = (const int*)d_in[5];

    const int B = 128;
    const int N = in_sizes[0] / B;   // 20000
    const int M = in_sizes[1] / B;   // 85400

    float* outC   = (float*)d_out;
    float* gradv  = outC   + (size_t)in_sizes[1];
    float* outdxl = gradv  + (size_t)in_sizes[0];
    float* outdxs = outdxl + (size_t)in_sizes[1];

    const size_t bn = (size_t)B * N;
    const size_t ws_need = (size_t)BPB * bn * sizeof(float);

    if (N <= NMAX && ws_size >= ws_need && (bn % 4) == 0) {
        float* partial = (float*)d_ws;
        // chunk: multiple of 8 so every 8-clause group is 16B-aligned
        const int chunk = (((M + BPB - 1) / BPB) + 7) & ~7;
        or_priv10<<<dim3(BPB * B), dim3(1024), 0, stream>>>(
            v, xl, xs, param, sign, idx, outC, outdxl, outdxs,
            (float*)partial, N, M, B, chunk);
        const int n4 = (int)(bn / 4);
        const int rblocks = min(2048, (n4 + 255) / 256);
        reduce2<<<dim3(rblocks), dim3(256), 0, stream>>>(
            (const float4v*)partial, (float4v*)gradv, n4, n4);
    } else {
        const int n4 = (int)(bn / 4);
        zero_f4<<<dim3((n4 + 255) / 256), dim3(256), 0, stream>>>((float4v*)gradv, n4);
        dim3 grid((M + 255) / 256, B);
        or_kernel<<<grid, dim3(256), 0, stream>>>(v, xl, xs, param, sign, idx,
                                                  outC, gradv, outdxl, outdxs, N, M);
    }
}